// Round 1
// baseline (164.143 us; speedup 1.0000x reference)
//
#include <hip/hip_runtime.h>

typedef __bf16 bf16;
typedef __attribute__((ext_vector_type(8)))  __bf16 bf16x8;
typedef __attribute__((ext_vector_type(4)))  __bf16 bf16x4;
typedef __attribute__((ext_vector_type(16))) float  f32x16;

#define LEN   2048
#define CH    64
#define HEADS 32            // bs * n_heads = 4 * 8
#define LDK   80            // LDS row stride (elems): 160 B, 16B-aligned, <=2-way banks
#define BT    128           // t-rows per block (32 per wave)
#define BS    64            // s-tile

// ---------------- prep 1: K -> K^T bf16 (per head: [s][c]) ----------------
__global__ __launch_bounds__(256) void prep_kt_kernel(const float* __restrict__ qkv,
                                                      bf16* __restrict__ kt) {
  __shared__ float tile[64][65];            // +1 pad: conflict-free both ways
  const int s0  = blockIdx.x * 64;
  const int g   = blockIdx.y;
  const int tid = threadIdx.x;
  const float* K = qkv + (g * 192 + 64) * LEN;   // K rows 64..127 of this head
  {
    const int c0 = tid >> 6, s = tid & 63;
#pragma unroll
    for (int i = 0; i < 16; ++i) {
      const int c = c0 + i * 4;
      tile[c][s] = K[c * LEN + s0 + s];     // coalesced along s
    }
  }
  __syncthreads();
  {
    const int r0 = tid >> 6, c = tid & 63;
    bf16* dst = kt + g * (LEN * CH);
#pragma unroll
    for (int i = 0; i < 16; ++i) {
      const int s = r0 + i * 4;
      dst[(s0 + s) * CH + c] = (bf16)tile[c][s];   // coalesced along c
    }
  }
}

// ---------------- prep 2: V -> bf16 (native [c][s]) ----------------
__global__ __launch_bounds__(256) void prep_v_kernel(const float* __restrict__ qkv,
                                                     bf16* __restrict__ vb) {
  const int i   = blockIdx.x * 256 + threadIdx.x;    // 1,048,576 float4 groups
  const int g   = i >> 15;                           // 32768 groups per head
  const int off = (i & 32767) * 4;
  const float4 v = *(const float4*)(qkv + (g * 192 + 128) * LEN + off);
  bf16x4 o;
  o[0] = (bf16)v.x; o[1] = (bf16)v.y; o[2] = (bf16)v.z; o[3] = (bf16)v.w;
  *(bf16x4*)(vb + g * (CH * LEN) + off) = o;
}

// ---------------- main: flash attention, S^T form ----------------
// S^T = K^T(64s x 64c) . Q(64c x 32t)  : A = Kt rows (LDS), B = Q frags (regs)
// O^T = V (64c x 64s)  . P^T(64s x 32t): A = V rows (LDS), B = P^T (wave LDS)
__global__ __launch_bounds__(256, 2) void attn_kernel(const float* __restrict__ qkv,
                                                      const bf16* __restrict__ kt,
                                                      const bf16* __restrict__ vb,
                                                      float* __restrict__ out) {
  __shared__ __align__(16) bf16 ktl[BS * LDK];
  __shared__ __align__(16) bf16 vl [CH * LDK];
  __shared__ __align__(16) bf16 pl [4 * 32 * LDK];   // per-wave P^T regions

  const int tid  = threadIdx.x;
  const int lane = tid & 63;
  const int w    = tid >> 6;
  const int g    = blockIdx.y;
  const int n    = lane & 31;      // MFMA col index = t (and m-row index for A frags)
  const int h    = lane >> 5;      // half-wave: k-offset selector
  const int t    = blockIdx.x * BT + w * 32 + n;

  // --- Q fragments as B-operand: B[k=c][n=t], k = kb*16 + h*8 + j. Loaded once.
  // Fold scale = ch^-0.5 * log2(e) so softmax runs in base-2 (v_exp_f32).
  const float qscale = 0.125f * 1.44269504088896340736f;
  const float* Q = qkv + g * (192 * LEN);
  bf16x8 qf[4];
#pragma unroll
  for (int kb = 0; kb < 4; ++kb) {
#pragma unroll
    for (int j = 0; j < 8; ++j) {
      const int c = kb * 16 + h * 8 + j;
      qf[kb][j] = (bf16)(Q[c * LEN + t] * qscale);   // quarter-wave coalesced (t contiguous)
    }
  }

  f32x16 o_acc[2];
#pragma unroll
  for (int mb = 0; mb < 2; ++mb)
#pragma unroll
    for (int r = 0; r < 16; ++r) o_acc[mb][r] = 0.f;

  float m_i = -INFINITY, l_i = 0.f;

  const bf16* ktg = kt + g * (LEN * CH);
  const bf16* vg  = vb + g * (CH * LEN);
  bf16* plw = pl + w * (32 * LDK);

  for (int s0 = 0; s0 < LEN; s0 += BS) {
    __syncthreads();                       // previous tile's LDS reads done
    // --- stage K^T tile (64s x 64c) and V tile (64c x 64s), both bf16 16B chunks
#pragma unroll
    for (int it = 0; it < 2; ++it) {
      const int chunk = tid + it * 256;    // 512 chunks of 16 B per tensor
      const int row   = chunk >> 3;
      const int coff  = (chunk & 7) * 8;
      *(bf16x8*)(ktl + row * LDK + coff) = *(const bf16x8*)(ktg + (s0 + row) * CH + coff);
      *(bf16x8*)(vl  + row * LDK + coff) = *(const bf16x8*)(vg + row * LEN + s0 + coff);
    }
    __syncthreads();

    // --- S^T tile: rows s (2 m-blocks of 32), cols t (32 per wave)
    f32x16 sf[2];
#pragma unroll
    for (int mb = 0; mb < 2; ++mb) {
      f32x16 acc;
#pragma unroll
      for (int r = 0; r < 16; ++r) acc[r] = 0.f;
#pragma unroll
      for (int kb = 0; kb < 4; ++kb) {
        const bf16x8 a = *(const bf16x8*)(ktl + (mb * 32 + n) * LDK + kb * 16 + h * 8);
        acc = __builtin_amdgcn_mfma_f32_32x32x16_bf16(a, qf[kb], acc, 0, 0, 0);
      }
      sf[mb] = acc;
    }

    // --- online softmax over s for fixed t = lane's column.
    // lane holds s = mb*32 + (r&3) + 8*(r>>2) + 4*h ; other half via shfl_xor(32)
    float vmax = sf[0][0];
#pragma unroll
    for (int mb = 0; mb < 2; ++mb)
#pragma unroll
      for (int r = 0; r < 16; ++r) vmax = fmaxf(vmax, sf[mb][r]);
    vmax = fmaxf(vmax, __shfl_xor(vmax, 32));
    const float m_new = fmaxf(m_i, vmax);
    const float alpha = exp2f(m_i - m_new);
    float rs = 0.f;
#pragma unroll
    for (int mb = 0; mb < 2; ++mb)
#pragma unroll
      for (int r = 0; r < 16; ++r) {
        const float p = exp2f(sf[mb][r] - m_new);
        sf[mb][r] = p;
        rs += p;
      }
    rs += __shfl_xor(rs, 32);
    l_i = l_i * alpha + rs;
    m_i = m_new;
#pragma unroll
    for (int mb = 0; mb < 2; ++mb)
#pragma unroll
      for (int r = 0; r < 16; ++r) o_acc[mb][r] *= alpha;

    // --- write P^T to wave-private LDS: layout [t][s], packed 4 consecutive s
#pragma unroll
    for (int mb = 0; mb < 2; ++mb)
#pragma unroll
      for (int rg = 0; rg < 4; ++rg) {
        bf16x4 p4;
#pragma unroll
        for (int e = 0; e < 4; ++e) p4[e] = (bf16)sf[mb][rg * 4 + e];
        const int sbase = mb * 32 + rg * 8 + h * 4;
        *(bf16x4*)(plw + n * LDK + sbase) = p4;     // ds_write_b64
      }
    // same-wave LDS ordering guarantees write->read visibility (no barrier needed)

    // --- O^T += V . P^T : A = V rows (c), B = P^T[k=s][n=t]
#pragma unroll
    for (int mb = 0; mb < 2; ++mb) {
      f32x16 acc = o_acc[mb];
#pragma unroll
      for (int kb = 0; kb < 4; ++kb) {
        const bf16x8 a = *(const bf16x8*)(vl  + (mb * 32 + n) * LDK + kb * 16 + h * 8);
        const bf16x8 b = *(const bf16x8*)(plw + n * LDK + kb * 16 + h * 8);
        acc = __builtin_amdgcn_mfma_f32_32x32x16_bf16(a, b, acc, 0, 0, 0);
      }
      o_acc[mb] = acc;
    }
  }

  // --- epilogue: O[c][t] / l, coalesced stores along t
  const float inv_l = 1.0f / l_i;
  float* og = out + g * (CH * LEN);
#pragma unroll
  for (int mb = 0; mb < 2; ++mb)
#pragma unroll
    for (int r = 0; r < 16; ++r) {
      const int c = mb * 32 + (r & 3) + 8 * (r >> 2) + 4 * h;
      og[c * LEN + t] = o_acc[mb][r] * inv_l;
    }
}

extern "C" void kernel_launch(void* const* d_in, const int* in_sizes, int n_in,
                              void* d_out, int out_size, void* d_ws, size_t ws_size,
                              hipStream_t stream) {
  const float* qkv = (const float*)d_in[0];
  float* out = (float*)d_out;

  // workspace: Kt bf16 (8 MB) | Vb bf16 (8 MB)
  bf16* ktw = (bf16*)d_ws;
  bf16* vbw = ktw + (size_t)HEADS * LEN * CH;

  prep_kt_kernel<<<dim3(LEN / 64, HEADS), 256, 0, stream>>>(qkv, ktw);
  prep_v_kernel<<<dim3((HEADS * CH * LEN) / (256 * 4)), 256, 0, stream>>>(qkv, vbw);
  attn_kernel<<<dim3(LEN / BT, HEADS), 256, 0, stream>>>(qkv, ktw, vbw, out);
}